// Round 7
// baseline (536.968 us; speedup 1.0000x reference)
//
#include <hip/hip_runtime.h>
#include <hip/hip_bf16.h>
#include <stdint.h>

#define NTOK 4096
#define DIM  256
#define NH   8
#define HD   32
#define KSPLIT 4     // waves per attention block
#define QTILE 32     // q-rows per block

typedef __attribute__((ext_vector_type(8))) short short8;
typedef __attribute__((ext_vector_type(4))) short short4v;
typedef __attribute__((ext_vector_type(4))) float float4v;
typedef unsigned short u16;
typedef unsigned int u32;

__device__ __forceinline__ float bf2f(u16 u) {
    union { u32 u; float f; } c; c.u = ((u32)u) << 16; return c.f;
}
__device__ __forceinline__ u16 f2bf(float f) {        // RNE (cold paths)
    union { float f; u32 u; } c; c.f = f;
    u32 u = c.u;
    u = u + 0x7FFFu + ((u >> 16) & 1u);
    return (u16)(u >> 16);
}
__device__ __forceinline__ u16 f2bf_fast(float f) {   // round-half-up (hot path)
    union { float f; u32 u; } c; c.f = f;
    return (u16)((c.u + 0x8000u) >> 16);
}

// ---------------- kernel A: x (f32) -> bf16 ----------------
__global__ void x_to_bf16(const float* __restrict__ x, u16* __restrict__ xb) {
    int i = (blockIdx.x * blockDim.x + threadIdx.x) * 4;
    float4 v = *(const float4*)(x + i);
    ushort4 o;
    o.x = f2bf(v.x); o.y = f2bf(v.y); o.z = f2bf(v.z); o.w = f2bf(v.w);
    *(ushort4*)(xb + i) = o;
}

// ---------------- kernel 0: transpose weights (f32 256x256 -> bf16 WT) ----------------
__global__ void transpose_w(const float* __restrict__ Wq, const float* __restrict__ Wk,
                            const float* __restrict__ Wv, const float* __restrict__ Wo,
                            u16* __restrict__ WT) {
    const float* srcs[4] = {Wq, Wk, Wv, Wo};
    const float* W = srcs[blockIdx.y];
    int o = blockIdx.x, i = threadIdx.x;
    WT[blockIdx.y * 65536 + o * 256 + i] = f2bf(W[i * 256 + o]);
}

// ---------------- kernel 1: adj (f32 0/1) -> bitmask via ballot ----------------
// 4096 workgroups x 16 iters (was 65536 single-iter WGs: dispatch-bound)
__global__ __launch_bounds__(256) void adj_to_bits(const float* __restrict__ adj,
                                                   u32* __restrict__ bits) {
    int t = threadIdx.x, lane = t & 63;
    size_t base = (size_t)blockIdx.x * 4096 + t;
#pragma unroll
    for (int c = 0; c < 16; ++c) {
        size_t i = base + c * 256;
        unsigned long long b = __ballot(adj[i] != 0.0f);
        if (lane == 0)       bits[i >> 5] = (u32)b;
        else if (lane == 32) bits[i >> 5] = (u32)(b >> 32);
    }
}

// ---------------- kernel 2: QKV projection ----------------
__global__ __launch_bounds__(64) void qkv_gemm(
    const u16* __restrict__ xb,
    const u16* __restrict__ WT,
    const float* __restrict__ bq, const float* __restrict__ bk, const float* __restrict__ bv,
    u16* __restrict__ Q, u16* __restrict__ K, u16* __restrict__ VT) {
    int lane = threadIdx.x, quad = lane >> 4, l16 = lane & 15;
    int mtile = blockIdx.x, ntile = blockIdx.y, mat = blockIdx.z;
    const float* bias = (mat == 0) ? bq : (mat == 1) ? bk : bv;
    const u16* xrow = xb + (size_t)(mtile * 16 + l16) * DIM + quad * 8;
    const u16* wrow = WT + (size_t)mat * 65536 + (size_t)(ntile * 16 + l16) * DIM + quad * 8;
    const u16* arow = (mat == 2) ? wrow : xrow;   // mat 2: A=W^T rows (n), B=x rows (m)
    const u16* brow = (mat == 2) ? xrow : wrow;
    float4v acc = {0.f, 0.f, 0.f, 0.f};
#pragma unroll
    for (int k0 = 0; k0 < DIM; k0 += 32) {
        short8 af = *(const short8*)(arow + k0);
        short8 bf = *(const short8*)(brow + k0);
        acc = __builtin_amdgcn_mfma_f32_16x16x32_bf16(af, bf, acc, 0, 0, 0);
    }
    if (mat == 2) {
#pragma unroll
        for (int r = 0; r < 4; ++r) {
            int n = ntile * 16 + quad * 4 + r;
            int m = mtile * 16 + l16;
            VT[(size_t)n * NTOK + m] = f2bf(acc[r] + bias[n]);
        }
    } else {
        int n = ntile * 16 + l16;
        float bb = bias[n];
        const float sc = (mat == 0) ? 0.25503635559913516f : 1.0f;  // 1/sqrt(32)*log2e
#pragma unroll
        for (int r = 0; r < 4; ++r) {
            int m = mtile * 16 + quad * 4 + r;
            u16 o = f2bf((acc[r] + bb) * sc);
            if (mat == 0) Q[(size_t)m * DIM + n] = o;
            else          K[(size_t)m * DIM + n] = o;
        }
    }
}

// ---------------- kernel 3: fixed-max attention, low-LDS for 8 blocks/CU ----------------
// grid (128 qtiles, 8 heads, 2 K-halves); block 4 waves; wave w: keys half*2048+w*512..+512
// Writes UNNORMALIZED O-partial plane (bf16) + L partials; merge_ao divides later
// (division by L commutes with summation and with the Wo projection).
// LDS = plds only (18.4 KB -> 8 blocks/CU); per-wave plds region reused as f32 staging
// for the block merge after the K-loop.
__global__ __launch_bounds__(256, 8) void attn_kernel(
    const u16* __restrict__ Q, const u16* __restrict__ K, const u16* __restrict__ VT,
    const u32* __restrict__ adjbits, u16* __restrict__ AOp, float* __restrict__ Lp) {
    __shared__ __align__(16) u16 plds[KSPLIT][QTILE * 72];   // 18432 B

    int tid = threadIdx.x;
    int w = tid >> 6, lane = tid & 63, quad = lane >> 4, l16 = lane & 15;
    int qtile = blockIdx.x, h = blockIdx.y, half = blockIdx.z;
    int qbase = qtile * QTILE;
    const float4v zf = {0.f, 0.f, 0.f, 0.f};

    // Q B-fragments (n=l16=query, k=quad*8 over HD)
    short8 qf[2];
    qf[0] = *(const short8*)(Q + (size_t)(qbase + l16) * DIM + h * HD + quad * 8);
    qf[1] = *(const short8*)(Q + (size_t)(qbase + 16 + l16) * DIM + h * HD + quad * 8);

    const int kbeg = half * 2048 + w * 512, kend = kbeg + 512;
    float lsum[2] = {0.f, 0.f};
    float4v o[2][2] = {{zf, zf}, {zf, zf}};   // [s][g]: O[q=s*16+quad*4+r][d=g*16+l16]

    const u32* abrow0 = adjbits + (size_t)(qbase + l16) * (NTOK / 32);
    const u32* abrow1 = abrow0 + 16 * (NTOK / 32);

    for (int k0 = kbeg; k0 < kend; k0 += 64) {
        short8 kf[4];
#pragma unroll
        for (int c = 0; c < 4; ++c)
            kf[c] = *(const short8*)(K + (size_t)(k0 + c * 16 + l16) * DIM + h * HD + quad * 8);
        short8 vf[2][2];
#pragma unroll
        for (int cc = 0; cc < 2; ++cc)
#pragma unroll
            for (int g = 0; g < 2; ++g)
                vf[cc][g] = *(const short8*)(VT + (size_t)(h * HD + g * 16 + l16) * NTOK
                                             + k0 + cc * 32 + quad * 8);
        uint2 w2s[2];
        w2s[0] = *(const uint2*)(abrow0 + (k0 >> 5));
        w2s[1] = *(const uint2*)(abrow1 + (k0 >> 5));

        float4v st[2][4];
#pragma unroll
        for (int s = 0; s < 2; ++s)
#pragma unroll
            for (int c = 0; c < 4; ++c)
                st[s][c] = __builtin_amdgcn_mfma_f32_16x16x32_bf16(kf[c], qf[s], zf, 0, 0, 0);

#pragma unroll
        for (int s = 0; s < 2; ++s) {
#pragma unroll
            for (int c = 0; c < 4; ++c) {
                u32 word = (c < 2) ? w2s[s].x : w2s[s].y;
                int sh = (c & 1) * 16 + quad * 4;
                float e0 = ((word >> (sh + 0)) & 1u) ? __builtin_amdgcn_exp2f(st[s][c][0]) : 0.f;
                float e1 = ((word >> (sh + 1)) & 1u) ? __builtin_amdgcn_exp2f(st[s][c][1]) : 0.f;
                float e2 = ((word >> (sh + 2)) & 1u) ? __builtin_amdgcn_exp2f(st[s][c][2]) : 0.f;
                float e3 = ((word >> (sh + 3)) & 1u) ? __builtin_amdgcn_exp2f(st[s][c][3]) : 0.f;
                lsum[s] += (e0 + e1) + (e2 + e3);
                short4v pb;
                pb[0] = (short)f2bf_fast(e0); pb[1] = (short)f2bf_fast(e1);
                pb[2] = (short)f2bf_fast(e2); pb[3] = (short)f2bf_fast(e3);
                *(short4v*)(&plds[w][(s * 16 + l16) * 72 + c * 16 + quad * 4]) = pb;
            }
            short8 pa0 = *(const short8*)(&plds[w][(s * 16 + l16) * 72 + 0  + quad * 8]);
            short8 pa1 = *(const short8*)(&plds[w][(s * 16 + l16) * 72 + 32 + quad * 8]);
            o[s][0] = __builtin_amdgcn_mfma_f32_16x16x32_bf16(pa0, vf[0][0], o[s][0], 0, 0, 0);
            o[s][1] = __builtin_amdgcn_mfma_f32_16x16x32_bf16(pa0, vf[0][1], o[s][1], 0, 0, 0);
            o[s][0] = __builtin_amdgcn_mfma_f32_16x16x32_bf16(pa1, vf[1][0], o[s][0], 0, 0, 0);
            o[s][1] = __builtin_amdgcn_mfma_f32_16x16x32_bf16(pa1, vf[1][1], o[s][1], 0, 0, 0);
        }
    }

    // ---- per-wave staging into own plds region (reused as f32: 1024 O + 32 L = 1152 f32) ----
    float* pw = (float*)(&plds[w][0]);
#pragma unroll
    for (int s = 0; s < 2; ++s) {
        float v = lsum[s];
        v += __shfl_xor(v, 16, 64);
        v += __shfl_xor(v, 32, 64);
        if (quad == 0) pw[1024 + s * 16 + l16] = v;
    }
#pragma unroll
    for (int s = 0; s < 2; ++s)
#pragma unroll
        for (int g = 0; g < 2; ++g)
#pragma unroll
            for (int r = 0; r < 4; ++r)
                pw[(s * 16 + quad * 4 + r) * 32 + g * 16 + l16] = o[s][g][r];
    __syncthreads();

    // ---- block merge of 4 wave-partials -> unnormalized plane + L partial ----
    const float* pall = (const float*)(&plds[0][0]);   // wave stride = 1152 floats
    u16* dst = AOp + (size_t)half * (NTOK * DIM);
#pragma unroll
    for (int i = 0; i < 4; ++i) {
        int e = tid + i * 256;
        int q = e >> 5, d = e & 31;
        float v = pall[0 * 1152 + q * 32 + d] + pall[1 * 1152 + q * 32 + d]
                + pall[2 * 1152 + q * 32 + d] + pall[3 * 1152 + q * 32 + d];
        dst[(size_t)(qbase + q) * DIM + h * HD + d] = f2bf(v);
    }
    if (tid < 32) {
        int q = tid;
        float Ls = pall[0 * 1152 + 1024 + q] + pall[1 * 1152 + 1024 + q]
                 + pall[2 * 1152 + 1024 + q] + pall[3 * 1152 + 1024 + q];
        Lp[half * (NTOK * NH) + (qbase + q) * NH + h] = Ls;
    }
}

// ---------------- kernel 3b: merge 2 half-planes, divide by L ----------------
__global__ __launch_bounds__(256) void merge_ao(const u16* __restrict__ AOp,
                                                const float* __restrict__ Lp,
                                                u16* __restrict__ AO) {
    int idx = (blockIdx.x * 256 + threadIdx.x) * 4;    // over 1048576 elems
    int q = idx >> 8, h = (idx & 255) >> 5;
    float L = Lp[q * NH + h] + Lp[NTOK * NH + q * NH + h];
    float inv = 1.0f / L;
    ushort4 a = *(const ushort4*)(AOp + idx);
    ushort4 b = *(const ushort4*)(AOp + NTOK * DIM + idx);
    ushort4 o;
    o.x = f2bf((bf2f(a.x) + bf2f(b.x)) * inv);
    o.y = f2bf((bf2f(a.y) + bf2f(b.y)) * inv);
    o.z = f2bf((bf2f(a.z) + bf2f(b.z)) * inv);
    o.w = f2bf((bf2f(a.w) + bf2f(b.w)) * inv);
    *(ushort4*)(AO + idx) = o;
}

// ---------------- kernel 4: output projection (f32 out) ----------------
__global__ __launch_bounds__(64) void out_gemm(
    const u16* __restrict__ AO, const u16* __restrict__ WTo, const float* __restrict__ bo,
    float* __restrict__ out) {
    int lane = threadIdx.x, quad = lane >> 4, l16 = lane & 15;
    int mtile = blockIdx.x, ntile = blockIdx.y;
    const u16* arow = AO + (size_t)(mtile * 16 + l16) * DIM + quad * 8;
    const u16* brow = WTo + (size_t)(ntile * 16 + l16) * DIM + quad * 8;
    float4v acc = {0.f, 0.f, 0.f, 0.f};
#pragma unroll
    for (int k0 = 0; k0 < DIM; k0 += 32) {
        short8 af = *(const short8*)(arow + k0);
        short8 bf = *(const short8*)(brow + k0);
        acc = __builtin_amdgcn_mfma_f32_16x16x32_bf16(af, bf, acc, 0, 0, 0);
    }
    int n = ntile * 16 + l16;
    float bb = bo[n];
#pragma unroll
    for (int r = 0; r < 4; ++r)
        out[(size_t)(mtile * 16 + quad * 4 + r) * DIM + n] = acc[r] + bb;
}

extern "C" void kernel_launch(void* const* d_in, const int* in_sizes, int n_in,
                              void* d_out, int out_size, void* d_ws, size_t ws_size,
                              hipStream_t stream) {
    const float* x   = (const float*)d_in[0];
    const float* adj = (const float*)d_in[1];
    const float* Wq  = (const float*)d_in[2];
    const float* bq  = (const float*)d_in[3];
    const float* Wk  = (const float*)d_in[4];
    const float* bk  = (const float*)d_in[5];
    const float* Wv  = (const float*)d_in[6];
    const float* bv  = (const float*)d_in[7];
    const float* Wo  = (const float*)d_in[8];
    const float* bo  = (const float*)d_in[9];

    char* ws = (char*)d_ws;
    const size_t MB = 1u << 20;
    u16* Q   = (u16*)(ws);                    // 2 MB
    u16* K   = (u16*)(ws + 2 * MB);           // 2 MB
    u16* VT  = (u16*)(ws + 4 * MB);           // 2 MB
    u16* AO  = (u16*)(ws + 6 * MB);           // 2 MB
    u32* AB  = (u32*)(ws + 8 * MB);           // 2 MB adjacency bitmask
    u16* WT  = (u16*)(ws + 10 * MB);          // 512 KB
    u16* XB  = (u16*)(ws + 10 * MB + 512 * 1024);   // 2 MB
    u16* AOp = (u16*)(ws + 13 * MB);          // 4 MB (2 half-planes bf16)
    float* Lp = (float*)(ws + 17 * MB);       // 256 KB (2 x 4096 x 8 f32)

    x_to_bf16<<<dim3(1024), 256, 0, stream>>>(x, XB);
    transpose_w<<<dim3(256, 4), 256, 0, stream>>>(Wq, Wk, Wv, Wo, WT);
    adj_to_bits<<<dim3(4096), 256, 0, stream>>>(adj, AB);
    qkv_gemm<<<dim3(256, 16, 3), 64, 0, stream>>>(XB, WT, bq, bk, bv, Q, K, VT);
    attn_kernel<<<dim3(128, 8, 2), 256, 0, stream>>>(Q, K, VT, AB, AOp, Lp);
    merge_ao<<<dim3(1024), 256, 0, stream>>>(AOp, Lp, AO);
    out_gemm<<<dim3(256, 16), 64, 0, stream>>>(AO, WT + 3 * 65536, bo, (float*)d_out);
}

// Round 8
// 242.444 us; speedup vs baseline: 2.2148x; 2.2148x over previous
//
#include <hip/hip_runtime.h>
#include <hip/hip_bf16.h>
#include <stdint.h>

#define NTOK 4096
#define DIM  256
#define NH   8
#define HD   32
#define KSPLIT 4     // waves per attention block
#define QTILE 32     // q-rows per block

typedef __attribute__((ext_vector_type(8))) short short8;
typedef __attribute__((ext_vector_type(4))) short short4v;
typedef __attribute__((ext_vector_type(4))) float float4v;
typedef unsigned short u16;
typedef unsigned int u32;

__device__ __forceinline__ float bf2f(u16 u) {
    union { u32 u; float f; } c; c.u = ((u32)u) << 16; return c.f;
}
__device__ __forceinline__ u16 f2bf(float f) {        // RNE (cold paths)
    union { float f; u32 u; } c; c.f = f;
    u32 u = c.u;
    u = u + 0x7FFFu + ((u >> 16) & 1u);
    return (u16)(u >> 16);
}
__device__ __forceinline__ u16 f2bf_fast(float f) {   // round-half-up (hot path)
    union { float f; u32 u; } c; c.f = f;
    return (u16)((c.u + 0x8000u) >> 16);
}

// ---------------- kernel A: x (f32) -> bf16 ----------------
__global__ void x_to_bf16(const float* __restrict__ x, u16* __restrict__ xb) {
    int i = (blockIdx.x * blockDim.x + threadIdx.x) * 4;
    float4 v = *(const float4*)(x + i);
    ushort4 o;
    o.x = f2bf(v.x); o.y = f2bf(v.y); o.z = f2bf(v.z); o.w = f2bf(v.w);
    *(ushort4*)(xb + i) = o;
}

// ---------------- kernel 0: transpose weights (f32 256x256 -> bf16 WT) ----------------
__global__ void transpose_w(const float* __restrict__ Wq, const float* __restrict__ Wk,
                            const float* __restrict__ Wv, const float* __restrict__ Wo,
                            u16* __restrict__ WT) {
    const float* srcs[4] = {Wq, Wk, Wv, Wo};
    const float* W = srcs[blockIdx.y];
    int o = blockIdx.x, i = threadIdx.x;
    WT[blockIdx.y * 65536 + o * 256 + i] = f2bf(W[i * 256 + o]);
}

// ---------------- kernel 1: adj (f32 0/1) -> bitmask via ballot ----------------
__global__ __launch_bounds__(256) void adj_to_bits(const float* __restrict__ adj,
                                                   u32* __restrict__ bits) {
    int t = threadIdx.x, lane = t & 63;
    size_t base = (size_t)blockIdx.x * 4096 + t;
#pragma unroll
    for (int c = 0; c < 16; ++c) {
        size_t i = base + c * 256;
        unsigned long long b = __ballot(adj[i] != 0.0f);
        if (lane == 0)       bits[i >> 5] = (u32)b;
        else if (lane == 32) bits[i >> 5] = (u32)(b >> 32);
    }
}

// ---------------- kernel 2: QKV projection ----------------
__global__ __launch_bounds__(64) void qkv_gemm(
    const u16* __restrict__ xb,
    const u16* __restrict__ WT,
    const float* __restrict__ bq, const float* __restrict__ bk, const float* __restrict__ bv,
    u16* __restrict__ Q, u16* __restrict__ K, u16* __restrict__ VT) {
    int lane = threadIdx.x, quad = lane >> 4, l16 = lane & 15;
    int mtile = blockIdx.x, ntile = blockIdx.y, mat = blockIdx.z;
    const float* bias = (mat == 0) ? bq : (mat == 1) ? bk : bv;
    const u16* xrow = xb + (size_t)(mtile * 16 + l16) * DIM + quad * 8;
    const u16* wrow = WT + (size_t)mat * 65536 + (size_t)(ntile * 16 + l16) * DIM + quad * 8;
    const u16* arow = (mat == 2) ? wrow : xrow;   // mat 2: A=W^T rows (n), B=x rows (m)
    const u16* brow = (mat == 2) ? xrow : wrow;
    float4v acc = {0.f, 0.f, 0.f, 0.f};
#pragma unroll
    for (int k0 = 0; k0 < DIM; k0 += 32) {
        short8 af = *(const short8*)(arow + k0);
        short8 bf = *(const short8*)(brow + k0);
        acc = __builtin_amdgcn_mfma_f32_16x16x32_bf16(af, bf, acc, 0, 0, 0);
    }
    if (mat == 2) {
#pragma unroll
        for (int r = 0; r < 4; ++r) {
            int n = ntile * 16 + quad * 4 + r;
            int m = mtile * 16 + l16;
            VT[(size_t)n * NTOK + m] = f2bf(acc[r] + bias[n]);
        }
    } else {
        int n = ntile * 16 + l16;
        float bb = bias[n];
        const float sc = (mat == 0) ? 0.25503635559913516f : 1.0f;  // 1/sqrt(32)*log2e
#pragma unroll
        for (int r = 0; r < 4; ++r) {
            int m = mtile * 16 + quad * 4 + r;
            u16 o = f2bf((acc[r] + bb) * sc);
            if (mat == 0) Q[(size_t)m * DIM + n] = o;
            else          K[(size_t)m * DIM + n] = o;
        }
    }
}

// ---------------- kernel 3: fixed-max attention, low-LDS, NO forced wave cap ----------------
// grid (128 qtiles, 8 heads, 2 K-halves); block 4 waves; wave w: keys half*2048+w*512..+512
// Writes UNNORMALIZED O-partial plane (bf16) + L partials; out_gemm divides later.
// LDS = plds only (18.4 KB -> 8 blocks/CU at ~60 VGPR). launch_bounds(256,4): VGPR
// budget 128 (compiler uses ~60, no spill); occupancy is LDS-limited, not VGPR-forced.
__global__ __launch_bounds__(256, 4) void attn_kernel(
    const u16* __restrict__ Q, const u16* __restrict__ K, const u16* __restrict__ VT,
    const u32* __restrict__ adjbits, u16* __restrict__ AOp, float* __restrict__ Lp) {
    __shared__ __align__(16) u16 plds[KSPLIT][QTILE * 72];   // 18432 B

    int tid = threadIdx.x;
    int w = tid >> 6, lane = tid & 63, quad = lane >> 4, l16 = lane & 15;
    int qtile = blockIdx.x, h = blockIdx.y, half = blockIdx.z;
    int qbase = qtile * QTILE;
    const float4v zf = {0.f, 0.f, 0.f, 0.f};

    short8 qf[2];
    qf[0] = *(const short8*)(Q + (size_t)(qbase + l16) * DIM + h * HD + quad * 8);
    qf[1] = *(const short8*)(Q + (size_t)(qbase + 16 + l16) * DIM + h * HD + quad * 8);

    const int kbeg = half * 2048 + w * 512, kend = kbeg + 512;
    float lsum[2] = {0.f, 0.f};
    float4v o[2][2] = {{zf, zf}, {zf, zf}};   // [s][g]: O[q=s*16+quad*4+r][d=g*16+l16]

    const u32* abrow0 = adjbits + (size_t)(qbase + l16) * (NTOK / 32);
    const u32* abrow1 = abrow0 + 16 * (NTOK / 32);

    for (int k0 = kbeg; k0 < kend; k0 += 64) {
        short8 kf[4];
#pragma unroll
        for (int c = 0; c < 4; ++c)
            kf[c] = *(const short8*)(K + (size_t)(k0 + c * 16 + l16) * DIM + h * HD + quad * 8);
        short8 vf[2][2];
#pragma unroll
        for (int cc = 0; cc < 2; ++cc)
#pragma unroll
            for (int g = 0; g < 2; ++g)
                vf[cc][g] = *(const short8*)(VT + (size_t)(h * HD + g * 16 + l16) * NTOK
                                             + k0 + cc * 32 + quad * 8);
        uint2 w2s[2];
        w2s[0] = *(const uint2*)(abrow0 + (k0 >> 5));
        w2s[1] = *(const uint2*)(abrow1 + (k0 >> 5));

        float4v st[2][4];
#pragma unroll
        for (int s = 0; s < 2; ++s)
#pragma unroll
            for (int c = 0; c < 4; ++c)
                st[s][c] = __builtin_amdgcn_mfma_f32_16x16x32_bf16(kf[c], qf[s], zf, 0, 0, 0);

#pragma unroll
        for (int s = 0; s < 2; ++s) {
#pragma unroll
            for (int c = 0; c < 4; ++c) {
                u32 word = (c < 2) ? w2s[s].x : w2s[s].y;
                int sh = (c & 1) * 16 + quad * 4;
                float e0 = ((word >> (sh + 0)) & 1u) ? __builtin_amdgcn_exp2f(st[s][c][0]) : 0.f;
                float e1 = ((word >> (sh + 1)) & 1u) ? __builtin_amdgcn_exp2f(st[s][c][1]) : 0.f;
                float e2 = ((word >> (sh + 2)) & 1u) ? __builtin_amdgcn_exp2f(st[s][c][2]) : 0.f;
                float e3 = ((word >> (sh + 3)) & 1u) ? __builtin_amdgcn_exp2f(st[s][c][3]) : 0.f;
                lsum[s] += (e0 + e1) + (e2 + e3);
                short4v pb;
                pb[0] = (short)f2bf_fast(e0); pb[1] = (short)f2bf_fast(e1);
                pb[2] = (short)f2bf_fast(e2); pb[3] = (short)f2bf_fast(e3);
                *(short4v*)(&plds[w][(s * 16 + l16) * 72 + c * 16 + quad * 4]) = pb;
            }
            short8 pa0 = *(const short8*)(&plds[w][(s * 16 + l16) * 72 + 0  + quad * 8]);
            short8 pa1 = *(const short8*)(&plds[w][(s * 16 + l16) * 72 + 32 + quad * 8]);
            o[s][0] = __builtin_amdgcn_mfma_f32_16x16x32_bf16(pa0, vf[0][0], o[s][0], 0, 0, 0);
            o[s][1] = __builtin_amdgcn_mfma_f32_16x16x32_bf16(pa0, vf[0][1], o[s][1], 0, 0, 0);
            o[s][0] = __builtin_amdgcn_mfma_f32_16x16x32_bf16(pa1, vf[1][0], o[s][0], 0, 0, 0);
            o[s][1] = __builtin_amdgcn_mfma_f32_16x16x32_bf16(pa1, vf[1][1], o[s][1], 0, 0, 0);
        }
    }

    // ---- per-wave staging into own plds region (reused as f32: 1024 O + 32 L) ----
    float* pw = (float*)(&plds[w][0]);
#pragma unroll
    for (int s = 0; s < 2; ++s) {
        float v = lsum[s];
        v += __shfl_xor(v, 16, 64);
        v += __shfl_xor(v, 32, 64);
        if (quad == 0) pw[1024 + s * 16 + l16] = v;
    }
#pragma unroll
    for (int s = 0; s < 2; ++s)
#pragma unroll
        for (int g = 0; g < 2; ++g)
#pragma unroll
            for (int r = 0; r < 4; ++r)
                pw[(s * 16 + quad * 4 + r) * 32 + g * 16 + l16] = o[s][g][r];
    __syncthreads();

    // ---- block merge of 4 wave-partials -> unnormalized plane + L partial ----
    const float* pall = (const float*)(&plds[0][0]);   // wave stride = 1152 floats
    u16* dst = AOp + (size_t)half * (NTOK * DIM);
#pragma unroll
    for (int i = 0; i < 4; ++i) {
        int e = tid + i * 256;
        int q = e >> 5, d = e & 31;
        float v = pall[0 * 1152 + q * 32 + d] + pall[1 * 1152 + q * 32 + d]
                + pall[2 * 1152 + q * 32 + d] + pall[3 * 1152 + q * 32 + d];
        dst[(size_t)(qbase + q) * DIM + h * HD + d] = f2bf(v);
    }
    if (tid < 32) {
        int q = tid;
        float Ls = pall[0 * 1152 + 1024 + q] + pall[1 * 1152 + 1024 + q]
                 + pall[2 * 1152 + 1024 + q] + pall[3 * 1152 + 1024 + q];
        Lp[half * (NTOK * NH) + (qbase + q) * NH + h] = Ls;
    }
}

// ---------------- kernel 4: output projection fused with half-merge + normalize ----------------
// A-fragment built on the fly: A[m][col] = (AOp0[m][col] + AOp1[m][col]) / L[m][col>>5]
// head index col>>5 = k0>>5 is compile-time constant per unrolled iteration.
__global__ __launch_bounds__(64) void out_gemm(
    const u16* __restrict__ AOp, const float* __restrict__ Lp,
    const u16* __restrict__ WTo, const float* __restrict__ bo,
    float* __restrict__ out) {
    int lane = threadIdx.x, quad = lane >> 4, l16 = lane & 15;
    int mtile = blockIdx.x, ntile = blockIdx.y;
    int m = mtile * 16 + l16;
    const u16* arow0 = AOp + (size_t)m * DIM + quad * 8;
    const u16* arow1 = arow0 + (size_t)NTOK * DIM;
    const u16* brow = WTo + (size_t)(ntile * 16 + l16) * DIM + quad * 8;
    const float* lrow0 = Lp + m * NH;
    const float* lrow1 = lrow0 + NTOK * NH;
    float4v acc = {0.f, 0.f, 0.f, 0.f};
#pragma unroll
    for (int k0 = 0; k0 < DIM; k0 += 32) {
        const int h = k0 >> 5;                     // compile-time per unrolled iter
        float inv = 1.0f / (lrow0[h] + lrow1[h]);
        ushort4 a0 = *(const ushort4*)(arow0 + k0);
        ushort4 a1 = *(const ushort4*)(arow0 + k0 + 4);
        ushort4 b0 = *(const ushort4*)(arow1 + k0);
        ushort4 b1 = *(const ushort4*)(arow1 + k0 + 4);
        short8 af;
        af[0] = (short)f2bf_fast((bf2f(a0.x) + bf2f(b0.x)) * inv);
        af[1] = (short)f2bf_fast((bf2f(a0.y) + bf2f(b0.y)) * inv);
        af[2] = (short)f2bf_fast((bf2f(a0.z) + bf2f(b0.z)) * inv);
        af[3] = (short)f2bf_fast((bf2f(a0.w) + bf2f(b0.w)) * inv);
        af[4] = (short)f2bf_fast((bf2f(a1.x) + bf2f(b1.x)) * inv);
        af[5] = (short)f2bf_fast((bf2f(a1.y) + bf2f(b1.y)) * inv);
        af[6] = (short)f2bf_fast((bf2f(a1.z) + bf2f(b1.z)) * inv);
        af[7] = (short)f2bf_fast((bf2f(a1.w) + bf2f(b1.w)) * inv);
        short8 bf = *(const short8*)(brow + k0);
        acc = __builtin_amdgcn_mfma_f32_16x16x32_bf16(af, bf, acc, 0, 0, 0);
    }
    int n = ntile * 16 + l16;
    float bb = bo[n];
#pragma unroll
    for (int r = 0; r < 4; ++r)
        out[(size_t)(mtile * 16 + quad * 4 + r) * DIM + n] = acc[r] + bb;
}

extern "C" void kernel_launch(void* const* d_in, const int* in_sizes, int n_in,
                              void* d_out, int out_size, void* d_ws, size_t ws_size,
                              hipStream_t stream) {
    const float* x   = (const float*)d_in[0];
    const float* adj = (const float*)d_in[1];
    const float* Wq  = (const float*)d_in[2];
    const float* bq  = (const float*)d_in[3];
    const float* Wk  = (const float*)d_in[4];
    const float* bk  = (const float*)d_in[5];
    const float* Wv  = (const float*)d_in[6];
    const float* bv  = (const float*)d_in[7];
    const float* Wo  = (const float*)d_in[8];
    const float* bo  = (const float*)d_in[9];

    char* ws = (char*)d_ws;
    const size_t MB = 1u << 20;
    u16* Q   = (u16*)(ws);                    // 2 MB
    u16* K   = (u16*)(ws + 2 * MB);           // 2 MB
    u16* VT  = (u16*)(ws + 4 * MB);           // 2 MB
    u32* AB  = (u32*)(ws + 8 * MB);           // 2 MB adjacency bitmask
    u16* WT  = (u16*)(ws + 10 * MB);          // 512 KB
    u16* XB  = (u16*)(ws + 10 * MB + 512 * 1024);   // 2 MB
    u16* AOp = (u16*)(ws + 13 * MB);          // 4 MB (2 half-planes bf16)
    float* Lp = (float*)(ws + 17 * MB);       // 256 KB (2 x 4096 x 8 f32)

    x_to_bf16<<<dim3(1024), 256, 0, stream>>>(x, XB);
    transpose_w<<<dim3(256, 4), 256, 0, stream>>>(Wq, Wk, Wv, Wo, WT);
    adj_to_bits<<<dim3(4096), 256, 0, stream>>>(adj, AB);
    qkv_gemm<<<dim3(256, 16, 3), 64, 0, stream>>>(XB, WT, bq, bk, bv, Q, K, VT);
    attn_kernel<<<dim3(128, 8, 2), 256, 0, stream>>>(Q, K, VT, AB, AOp, Lp);
    out_gemm<<<dim3(256, 16), 64, 0, stream>>>(AOp, Lp, WT + 3 * 65536, bo, (float*)d_out);
}